// Round 2
// baseline (336.364 us; speedup 1.0000x reference)
//
#include <hip/hip_runtime.h>

// SoftDTW: B=64, M=N=512, gamma=0.01, P=2.
// Chunked-skew wavefront pipeline:
//   - 64 blocks (one per batch), 256 threads = 4 waves.
//   - Wave w owns columns [128w, 128w+127]; lane l owns cols jA=128w+2l, jB=jA+1.
//   - Wave processes D=16 consecutive diagonals per macro-step, all state in
//     registers; left-neighbor values via __shfl_up (wave-synchronous).
//   - Strip boundary (col 128w+127) published per-diagonal into a 64-entry LDS
//     ring by lane 63; next wave prefetches the window once per chunk.
//   - Skew: at macro-step s, wave w processes chunk c = s - w. One
//     __syncthreads per macro-step (67 total vs 1023 before).

#define BIGF 1e30f

__global__ __launch_bounds__(256) void softdtw_kernel(
    const float* __restrict__ x, const float* __restrict__ y,
    float* __restrict__ out)
{
    constexpr int N = 512;
    constexpr int D = 16;                 // diagonals per chunk
    constexpr int NC = 64;                // ceil(1023 / D)
    constexpr int W = 4;                  // waves per block
    constexpr int NSTEPS = NC + W - 1;    // 67

    const int b = blockIdx.x;
    const int tid = threadIdx.x;
    const int w = tid >> 6;
    const int lane = tid & 63;

    __shared__ float ylds[N];
    __shared__ float bnd[W][64];          // per-wave boundary ring, slot = d & 63

    const int jA = 128 * w + 2 * lane;    // first owned column
    const float xA = x[b * N + jA];
    const float xB = x[b * N + jA + 1];
    ylds[tid] = y[b * N + tid];
    ylds[tid + 256] = y[b * N + tid + 256];
    __syncthreads();

    // softmin_g(a,b,c) = m - g*ln(sum exp((m-a_i)/g)), m = min3
    // exp((m-a)/g) = exp2((m-a)*K), K = 100*log2(e); g*ln(S) = C*log2(S), C = 0.01*ln2
    const float K = 144.26950408889634f;
    const float C = 0.006931471805599453f;

    // register state: own columns' R on the previous two diagonals
    float r1A = BIGF, r2A = BIGF;         // col jA, diag d-1 / d-2
    float r1B = BIGF, r2B = BIGF;         // col jB
    float yprev = 0.0f;                   // y[clamp(iA)] from previous diagonal
    float edge_prev = BIGF;               // boundary value for diag d-2 (lane 0's rd)

    for (int s = 0; s < NSTEPS; ++s) {
        const int c = s - w;
        if (c >= 0 && c < NC) {
            const int d0 = D * c;
            // prefetch boundary window: lane l holds wave (w-1)'s col value on diag d0-2+l
            float pre;
            if (w == 0) {
                pre = (c == 0 && lane == 0) ? 0.0f : BIGF;  // R[-1,-1]=0 seed, else col -1 = BIG
            } else {
                pre = bnd[w - 1][(unsigned)(d0 - 2 + lane) & 63u];
            }
            edge_prev = __shfl(pre, 0);   // diag d0-2

#pragma unroll
            for (int t = 0; t < D; ++t) {
                const int d = d0 + t;
                if (d < 2 * N - 1) {
                    const int iA = d - jA;                       // row of cell A
                    const int iyA = min(max(iA, 0), N - 1);
                    const float yA = ylds[iyA];
                    const float yB = yprev;                      // = y[clamp(iA-1)]

                    // neighbor R values (captured before state rotation)
                    const float sh1 = __shfl_up(r1B, 1);         // left lane's col 2l-1, diag d-1
                    const float sh2 = __shfl_up(r2B, 1);         // diag d-2
                    const float rl_edge = __shfl(pre, t + 1);    // boundary, diag d-1
                    const float rlA = (lane == 0) ? rl_edge  : sh1;
                    const float rdA = (lane == 0) ? edge_prev : sh2;

                    // cell A = (iA, jA): rd=rdA, ru=r1A, rl=rlA
                    const float diffA = xA - yA;
                    const float dA = diffA * diffA;
                    const float mA = fminf(rdA, fminf(r1A, rlA));
                    const float sA = exp2f((mA - rdA) * K)
                                   + exp2f((mA - r1A) * K)
                                   + exp2f((mA - rlA) * K);
                    float vA = dA + mA - C * log2f(sA);
                    vA = ((unsigned)iA < (unsigned)N) ? vA : BIGF;

                    // cell B = (iA-1, jB): rd=r2A, ru=r1B, rl=r1A (all in-register)
                    const float diffB = xB - yB;
                    const float dB = diffB * diffB;
                    const float mB = fminf(r2A, fminf(r1B, r1A));
                    const float sB = exp2f((mB - r2A) * K)
                                   + exp2f((mB - r1B) * K)
                                   + exp2f((mB - r1A) * K);
                    float vB = dB + mB - C * log2f(sB);
                    vB = ((unsigned)(iA - 1) < (unsigned)N) ? vB : BIGF;

                    // publish strip boundary (col 128w+127) for next wave
                    if (lane == 63) bnd[w][d & 63] = vB;

                    // rotate state
                    r2A = r1A; r1A = vA;
                    r2B = r1B; r1B = vB;
                    yprev = yA;
                    edge_prev = rl_edge;
                }
            }
        }
        __syncthreads();
    }

    // R[511,511] lives in (wave 3, lane 63)'s cell B after diag 1022
    if (tid == 255) out[b] = r1B;
}

extern "C" void kernel_launch(void* const* d_in, const int* in_sizes, int n_in,
                              void* d_out, int out_size, void* d_ws, size_t ws_size,
                              hipStream_t stream) {
    const float* x = (const float*)d_in[0];  // [64, 512]
    const float* y = (const float*)d_in[1];  // [64, 512]
    float* out = (float*)d_out;              // [64]
    softdtw_kernel<<<64, 256, 0, stream>>>(x, y, out);
}

// Round 3
// 283.190 us; speedup vs baseline: 1.1878x; 1.1878x over previous
//
#include <hip/hip_runtime.h>

// SoftDTW: B=64, M=N=512, gamma=0.01, P=2.
// Chunked-skew wavefront pipeline, DPP edition:
//   - 64 blocks (one per batch), 256 threads = 4 waves.
//   - Wave w owns columns [128w, 128w+127]; lane l owns cols jA=128w+2l, jB=jA+1.
//   - D=16 diagonals per macro-step, all state in registers.
//   - Left-neighbor exchange via DPP wave_shr:1 (VALU op, no LDS pipe!)
//     instead of ds_bpermute — this is the per-diagonal latency chain.
//   - Strip boundary published into a 64-entry LDS ring by lane 63; next wave
//     prefetches the window once per chunk, broadcasts via v_readlane.

#define BIGF 1e30f

__device__ __forceinline__ float dpp_shr1(float v) {
    // dst[lane] = src[lane-1]; lane 0 keeps old (overridden by edge cndmask)
    int i = __float_as_int(v);
    int r = __builtin_amdgcn_update_dpp(i, i, 0x138 /*WAVE_SHR1*/, 0xF, 0xF, false);
    return __int_as_float(r);
}

__device__ __forceinline__ float rdlane(float v, int l) {
    return __int_as_float(__builtin_amdgcn_readlane(__float_as_int(v), l));
}

__global__ __launch_bounds__(256) void softdtw_kernel(
    const float* __restrict__ x, const float* __restrict__ y,
    float* __restrict__ out)
{
    constexpr int N = 512;
    constexpr int D = 16;                 // diagonals per chunk
    constexpr int NC = 64;                // 1024 / D
    constexpr int W = 4;                  // waves per block
    constexpr int NSTEPS = NC + W - 1;    // 67

    const int b = blockIdx.x;
    const int tid = threadIdx.x;
    const int w = tid >> 6;
    const int lane = tid & 63;

    __shared__ float ylds[N];
    __shared__ float bnd[W][64];          // per-wave boundary ring, slot = d & 63

    const int jA = 128 * w + 2 * lane;    // first owned column
    const float xA = x[b * N + jA];
    const float xB = x[b * N + jA + 1];
    ylds[tid] = y[b * N + tid];
    ylds[tid + 256] = y[b * N + tid + 256];
    __syncthreads();

    // softmin_g(a,b,c) = m - g*ln(sum exp((m-a_i)/g)), m = min3
    // exp((m-a)/g) = exp2((m-a)*K), K = 100*log2(e); g*ln(S) = C*log2(S), C = 0.01*ln2
    const float K = 144.26950408889634f;
    const float C = 0.006931471805599453f;

    float r1A = BIGF, r2A = BIGF;         // col jA, diag d-1 / d-2
    float r1B = BIGF, r2B = BIGF;         // col jB
    float yprev = 0.0f;                   // y[clamp(iA)] from previous diagonal
    float edge_prev = BIGF;               // boundary value, diag d-2
    float sh_prev = BIGF;                 // dpp_shr1(r1B) from previous diagonal

    for (int s = 0; s < NSTEPS; ++s) {
        const int c = s - w;
        if (c >= 0 && c < NC) {
            const int d0 = D * c;
            // boundary window: lane l = wave (w-1)'s strip-edge value on diag d0-2+l
            float pre;
            if (w == 0) {
                pre = (c == 0 && lane == 0) ? 0.0f : BIGF;  // R[-1,-1]=0 seed
            } else {
                pre = bnd[w - 1][(unsigned)(d0 - 2 + lane) & 63u];
            }
            edge_prev = rdlane(pre, 0);   // diag d0-2

#pragma unroll
            for (int t = 0; t < D; ++t) {
                const int d = d0 + t;
                if (d < 2 * N - 1) {
                    const int iA = d - jA;                       // row of cell A
                    const int iyA = min(max(iA, 0), N - 1);
                    const float yA = ylds[iyA];
                    const float yB = yprev;                      // = y[clamp(iA-1)]

                    // neighbor R values — DPP (VALU) not bpermute (LDS)
                    const float sh1 = dpp_shr1(r1B);             // left col, diag d-1
                    const float sh2 = sh_prev;                   // left col, diag d-2
                    const float rl_edge = rdlane(pre, t + 1);    // boundary, diag d-1
                    const float rlA = (lane == 0) ? rl_edge  : sh1;
                    const float rdA = (lane == 0) ? edge_prev : sh2;

                    // cell A = (iA, jA): rd=rdA, ru=r1A, rl=rlA
                    const float diffA = xA - yA;
                    const float dA = diffA * diffA;
                    const float mA = fminf(rdA, fminf(r1A, rlA));
                    const float sA = exp2f((mA - rdA) * K)
                                   + exp2f((mA - r1A) * K)
                                   + exp2f((mA - rlA) * K);
                    float vA = dA + mA - C * log2f(sA);
                    vA = ((unsigned)iA < (unsigned)N) ? vA : BIGF;

                    // cell B = (iA-1, jB): rd=r2A, ru=r1B, rl=r1A (all in-register,
                    // pre-rotation values → independent of vA this diagonal)
                    const float diffB = xB - yB;
                    const float dB = diffB * diffB;
                    const float mB = fminf(r2A, fminf(r1B, r1A));
                    const float sB = exp2f((mB - r2A) * K)
                                   + exp2f((mB - r1B) * K)
                                   + exp2f((mB - r1A) * K);
                    float vB = dB + mB - C * log2f(sB);
                    vB = ((unsigned)(iA - 1) < (unsigned)N) ? vB : BIGF;

                    // publish strip boundary (col 128w+127) for next wave
                    if (lane == 63) bnd[w][d & 63] = vB;

                    // rotate state
                    r2A = r1A; r1A = vA;
                    r2B = r1B; r1B = vB;
                    yprev = yA;
                    edge_prev = rl_edge;
                    sh_prev = sh1;
                }
            }
        }
        __syncthreads();
    }

    // R[511,511] lives in (wave 3, lane 63)'s cell B after diag 1022
    if (tid == 255) out[b] = r1B;
}

extern "C" void kernel_launch(void* const* d_in, const int* in_sizes, int n_in,
                              void* d_out, int out_size, void* d_ws, size_t ws_size,
                              hipStream_t stream) {
    const float* x = (const float*)d_in[0];  // [64, 512]
    const float* y = (const float*)d_in[1];  // [64, 512]
    float* out = (float*)d_out;              // [64]
    softdtw_kernel<<<64, 256, 0, stream>>>(x, y, out);
}

// Round 4
// 163.131 us; speedup vs baseline: 2.0619x; 1.7360x over previous
//
#include <hip/hip_runtime.h>

// SoftDTW: B=64, M=N=512, gamma=0.01, P=2.
// Chunked-skew wavefront pipeline, native-transcendental edition:
//   - 64 blocks (one per batch), 256 threads = 4 waves on 4 SIMDs.
//   - Wave w owns cols [128w,128w+127]; lane l owns jA=128w+2l, jB=jA+1.
//   - D=32 diagonals per macro-step, all state in registers.
//   - Left-neighbor via DPP wave_shr:1 (VALU); boundary via LDS ring + readlane.
//   - softmin via min3/med3/max3: s = 1 + e^((m-med)/g) + e^((m-max)/g)
//     -> 2 native v_exp_f32 + 1 native v_log_f32 per cell.
//   - y window preloaded into 32 registers per chunk from padded ylds.

#define BIGF 1e30f

__device__ __forceinline__ float dpp_shr1(float v) {
    int i = __float_as_int(v);
    int r = __builtin_amdgcn_update_dpp(i, i, 0x138 /*WAVE_SHR1*/, 0xF, 0xF, false);
    return __int_as_float(r);
}
__device__ __forceinline__ float rdlane(float v, int l) {
    return __int_as_float(__builtin_amdgcn_readlane(__float_as_int(v), l));
}

__global__ __launch_bounds__(256) void softdtw_kernel(
    const float* __restrict__ x, const float* __restrict__ y,
    float* __restrict__ out)
{
    constexpr int N = 512;
    constexpr int D = 32;                 // diagonals per chunk
    constexpr int NC = 32;                // chunks (covers diag 0..1023; 1023 harmless)
    constexpr int W = 4;
    constexpr int NSTEPS = NC + W - 1;    // 35
    constexpr int PAD = 64;

    const int b = blockIdx.x;
    const int tid = threadIdx.x;
    const int w = tid >> 6;
    const int lane = tid & 63;

    __shared__ float ylds[N + 2 * PAD];   // padded: index PAD + i, i in [-64, N+63]
    __shared__ float bnd[W][64];          // per-wave boundary ring, slot = d & 63

    const int jA = 128 * w + 2 * lane;
    const float xA = x[b * N + jA];
    const float xB = x[b * N + jA + 1];
    for (int k = tid; k < N + 2 * PAD; k += 256) {
        int i = k - PAD;
        ylds[k] = ((unsigned)i < (unsigned)N) ? y[b * N + i] : 0.0f;
    }
    __syncthreads();

    const float K = 144.26950408889634f;   // 100 * log2(e)
    const float C = 0.006931471805599453f; // 0.01 * ln(2)
    const bool is0 = (lane == 0);

    float r1A = BIGF, r2A = BIGF;          // col jA, diag d-1 / d-2
    float r1B = BIGF, r2B = BIGF;          // col jB
    float yprev = 0.0f;                    // y[iA-1] carried across iterations/chunks
    float edge_prev = BIGF;                // boundary value, diag d-2
    float sh_prev = BIGF;                  // dpp_shr1(r1B) from previous diagonal

    for (int s = 0; s < NSTEPS; ++s) {
        const int c = s - w;
        if (c >= 0 && c < NC) {
            const int d0 = D * c;

            // ---- preload y window (off the dependent chain) ----
            const int iA0 = d0 - jA;
            int base = iA0 < -PAD ? -PAD : (iA0 > N + PAD - D ? N + PAD - D : iA0);
            // clamp only fires when ALL cells in chunk are out-of-range (-> BIG anyway)
            float yw[D];
#pragma unroll
            for (int t = 0; t < D; ++t) yw[t] = ylds[PAD + base + t];

            // ---- boundary window from previous wave ----
            float pre;
            if (w == 0) {
                pre = (c == 0 && lane == 0) ? 0.0f : BIGF;  // R[-1,-1]=0 seed
            } else {
                pre = bnd[w - 1][(unsigned)(d0 - 2 + lane) & 63u];
            }
            edge_prev = rdlane(pre, 0);

#pragma unroll
            for (int t = 0; t < D; ++t) {
                const int d = d0 + t;
                const int iA = d - jA;
                const float yA = yw[t];
                const float yB = yprev;

                const float sh1 = dpp_shr1(r1B);          // left col, diag d-1
                const float rl_edge = rdlane(pre, t + 1); // boundary, diag d-1
                const float rlA = is0 ? rl_edge : sh1;
                const float rdA = is0 ? edge_prev : sh_prev;

                // cell A = (iA, jA): rd=rdA, ru=r1A, rl=rlA
                const float diffA = xA - yA;
                const float dA = diffA * diffA;
                const float mA   = fminf(rdA, fminf(r1A, rlA));
                const float medA = __builtin_amdgcn_fmed3f(rdA, r1A, rlA);
                const float MA   = fmaxf(rdA, fmaxf(r1A, rlA));
                const float mKA = mA * K;
                const float e1A = __builtin_amdgcn_exp2f(fmaf(medA, -K, mKA));
                const float e2A = __builtin_amdgcn_exp2f(fmaf(MA,   -K, mKA));
                const float lA  = __builtin_amdgcn_logf((1.0f + e1A) + e2A);
                float vA = fmaf(-C, lA, dA + mA);
                vA = ((unsigned)iA < (unsigned)N) ? vA : BIGF;

                // cell B = (iA-1, jB): rd=r2A, ru=r1B, rl=r1A (all in-register)
                const float diffB = xB - yB;
                const float dB = diffB * diffB;
                const float mB   = fminf(r2A, fminf(r1B, r1A));
                const float medB = __builtin_amdgcn_fmed3f(r2A, r1B, r1A);
                const float MB   = fmaxf(r2A, fmaxf(r1B, r1A));
                const float mKB = mB * K;
                const float e1B = __builtin_amdgcn_exp2f(fmaf(medB, -K, mKB));
                const float e2B = __builtin_amdgcn_exp2f(fmaf(MB,   -K, mKB));
                const float lB  = __builtin_amdgcn_logf((1.0f + e1B) + e2B);
                float vB = fmaf(-C, lB, dB + mB);
                vB = ((unsigned)(iA - 1) < (unsigned)N) ? vB : BIGF;

                // publish strip boundary (col 128w+127) for next wave
                if (lane == 63) bnd[w][d & 63] = vB;

                // rotate state
                r2A = r1A; r1A = vA;
                r2B = r1B; r1B = vB;
                yprev = yA;
                edge_prev = rl_edge;
                sh_prev = sh1;
            }
        }
        __syncthreads();
    }

    // diag 1022 put R[511,511] into (wave3,lane63).r1B; diag 1023 rotated it to r2B
    if (tid == 255) out[b] = r2B;
}

extern "C" void kernel_launch(void* const* d_in, const int* in_sizes, int n_in,
                              void* d_out, int out_size, void* d_ws, size_t ws_size,
                              hipStream_t stream) {
    const float* x = (const float*)d_in[0];  // [64, 512]
    const float* y = (const float*)d_in[1];  // [64, 512]
    float* out = (float*)d_out;              // [64]
    softdtw_kernel<<<64, 256, 0, stream>>>(x, y, out);
}